// Round 17
// baseline (103.395 us; speedup 1.0000x reference)
//
#include <hip/hip_runtime.h>
#include <math.h>

#define TT 1024
#define NN 64
#define CC 128
#define SS 128
#define CH 32
#define NCHUNK 32
#define NC (NN * CC)

typedef float f4 __attribute__((ext_vector_type(4)));

// DPP controls (gfx9/CDNA encodings)
#define DPP_QP_XOR1   0xB1
#define DPP_QP_XOR2   0x4E
#define DPP_WAVE_SHR1 0x138
#define DPP_ROW_MIRR  0x140
#define DPP_HALF_MIRR 0x141
#define DPP_BCAST15   0x142
#define DPP_BCAST31   0x143

template <int CTRL>
__device__ __forceinline__ float dpp_max_stage(float v) {
    int p = __builtin_amdgcn_update_dpp(__float_as_int(v), __float_as_int(v),
                                        CTRL, 0xF, 0xF, false);
    return fmaxf(v, __int_as_float(p));
}
__device__ __forceinline__ float dpp_shr1(float v) {
    int p = __builtin_amdgcn_update_dpp(0, __float_as_int(v),
                                        DPP_WAVE_SHR1, 0xF, 0xF, true);
    return __int_as_float(p);
}

#define DSR(dst, addr, off) \
    asm volatile("ds_read_b128 %0, %1 offset:" #off : "=v"(dst) : "v"(addr))
#define LGKM(n) do { \
    asm volatile("s_waitcnt lgkmcnt(" #n ")" ::: "memory"); \
    __builtin_amdgcn_sched_barrier(0); } while (0)
#define VMC(n) do { \
    asm volatile("s_waitcnt vmcnt(" #n ")" ::: "memory"); \
    __builtin_amdgcn_sched_barrier(0); } while (0)
#define BARRIER() asm volatile("s_barrier" ::: "memory")

// ---------------------------------------------------------------------------
// Kernel A: parallel emission pack (round-3 verified logic, n-major index).
// E[n][t][lane] = {exp(lp[t,n,0]), exp(lp[t,n,tgA]), exp(lp[t,n,tgB]), 0}
__global__ __launch_bounds__(256) void ctc_emit(
    const float* __restrict__ lp,
    const int*   __restrict__ targets,
    float4*      __restrict__ E)
{
    const int wid  = blockIdx.x * 4 + (threadIdx.x >> 6);
    const int lane = threadIdx.x & 63;
    const int t = wid & (TT - 1);
    const int n = wid >> 10;

    const float* row = lp + ((size_t)t * NN + n) * CC;
    const int tgA = targets[n * SS + 2 * lane];
    const int tgB = targets[n * SS + 2 * lane + 1];

    const float pb = __expf(row[0]);      // broadcast load
    const float pa = __expf(row[tgA]);
    const float pc = __expf(row[tgB]);
    E[(((size_t)n << 10) + t) * 64 + lane] = make_float4(pb, pa, pc, 0.f);
}

// ---------------------------------------------------------------------------
// Kernel B: LONE-WAVE serial scan, verified primitives only.
// One wave per n. Self-staged E via global_load_lds into a 16-slot LDS ring
// (two halves of 8 slots; refill writes the opposite half -> no WAR race,
// no barriers). Counted VMC(28) keeps 8 groups (32 loads) in flight.
// Plain-C LDS reads AFTER the "memory"-clobber wait (r9-verified safe).
__global__ __launch_bounds__(64) void ctc_scan_lone(
    const float4* __restrict__ E,
    const int*    __restrict__ targets,
    const int*    __restrict__ ilen,
    const int*    __restrict__ tlen,
    float*        __restrict__ v_out)
{
    const int n    = blockIdx.x;
    const int lane = threadIdx.x;

    __shared__ float4 ring[16][4][64];   // 64 KiB: [slot][c][lane]

    const int tgA  = targets[n * SS + 2 * lane];
    const int tgB  = targets[n * SS + 2 * lane + 1];
    const int tgBm = (lane > 0) ? targets[n * SS + 2 * lane - 1] : -1;
    const float k1f = (lane > 0 && tgA != tgBm) ? 1.f : 0.f;
    const float k3f = (tgB != tgA) ? 1.f : 0.f;

    const int il    = ilen[n];
    const int vs    = 2 * tlen[n] - 1;   // odd, in [127, 255]
    const int vlane = vs >> 2;

    const float4* En = E + (((size_t)n) << 10) * 64;   // row t at En + t*64

    // drain the targets/len loads so vmcnt counts ONLY the pipeline below
    VMC(0);

    // prologue: groups 0..7 -> slots 0..7 (32 gload_lds in flight)
#pragma unroll
    for (int g = 0; g < 8; ++g) {
#pragma unroll
        for (int c = 0; c < 4; ++c) {
            const float* src = (const float*)(En + (size_t)(4 * g + c) * 64) + lane * 4;
            __builtin_amdgcn_global_load_lds(
                (const __attribute__((address_space(1))) void*)src,
                (__attribute__((address_space(3))) void*)&ring[g][c][0],
                16, 0, 0);
        }
    }

    float a0 = 1.f, a1 = 1.f, a2 = 1.f, a3 = 1.f, ls = 0.f;
    float a3p = (lane == 0) ? 0.f : 1.f;
    float mr = 1.f, inv = 1.f;

    for (int og = 0; og < 32; ++og) {
        const int wh = ((og + 1) & 1) << 3;     // half to refill (runtime)
        const int rh = (og & 1) << 3;           // half to read   (runtime)
#pragma unroll
        for (int i = 0; i < 8; ++i) {
            const int g   = og * 8 + i;
            const int t0g = 4 * g;
            VMC(28);                            // oldest group (g) landed in LDS

            // read this group's 4 rows (plain C: cannot hoist above VMC)
            const float4 e0 = ring[rh + i][0][lane];
            const float4 e1 = ring[rh + i][1][lane];
            const float4 e2 = ring[rh + i][2][lane];
            const float4 e3 = ring[rh + i][3][lane];

            // refill opposite half with group g+8 (clamped; tail unconsumed)
            {
                int gn = g + 8; if (gn > 255) gn = 255;
#pragma unroll
                for (int c = 0; c < 4; ++c) {
                    const float* src =
                        (const float*)(En + (size_t)(4 * gn + c) * 64) + lane * 4;
                    __builtin_amdgcn_global_load_lds(
                        (const __attribute__((address_space(1))) void*)src,
                        (__attribute__((address_space(3))) void*)&ring[wh + i][c][0],
                        16, 0, 0);
                }
                __builtin_amdgcn_sched_barrier(0);   // keep issue early
            }

            const bool cap = ((unsigned)(il - 1 - t0g) < 4u);
#pragma unroll
            for (int c = 0; c < 4; ++c) {
                const int t = t0g + c;
                const float4 e = (c == 0) ? e0 : (c == 1) ? e1 : (c == 2) ? e2 : e3;
                if (g == 0 && c == 0) {
                    // t = 0 init (reference: alpha0 zeros except s=0,1)
                    a0 = (lane == 0) ? e.x : 1.f;   // pb(0)
                    a1 = (lane == 0) ? e.y : 1.f;   // pa(0)
                    continue;
                }
                const float cpb = e.x, cpa = e.y, cpc = e.z;

                float nb3 = fmaf(k3f, a1, a3 + a2) * cpc;
                float a3pn = dpp_shr1(nb3);
                float nb0 = (a0 + a3p) * cpb;
                float nb1 = fmaf(k1f, a3p, a0 + a1) * cpa;
                float nb2 = (a2 + a1) * cpb;

                const int jj = (i & 1) * 4 + c;   // == t & 7 (compile-time)
                if      (jj == 0) mr = fmaxf(fmaxf(nb0, nb1), fmaxf(nb2, nb3));
                else if (jj == 1) mr = dpp_max_stage<DPP_QP_XOR1>(mr);
                else if (jj == 2) mr = dpp_max_stage<DPP_QP_XOR2>(mr);
                else if (jj == 3) mr = dpp_max_stage<DPP_HALF_MIRR>(mr);
                else if (jj == 4) mr = dpp_max_stage<DPP_ROW_MIRR>(mr);
                else if (jj == 5) mr = dpp_max_stage<DPP_BCAST15>(mr);
                else if (jj == 6) mr = dpp_max_stage<DPP_BCAST31>(mr);
                else {
                    const float mru = __int_as_float(
                        __builtin_amdgcn_readlane(__float_as_int(mr), 63));
                    inv = 1.0f / mru;
                    ls += __logf(mru);
                    nb0 *= inv; nb1 *= inv; nb2 *= inv; nb3 *= inv;
                }

                if (cap) {
                    if (t == il - 1 && lane == vlane)
                        v_out[n] = __logf((vs & 2) ? nb3 : nb1) + ls;
                }

                a0 = nb0; a1 = nb1; a2 = nb2; a3 = nb3;
                if (jj == 7) a3pn *= inv;
                a3p = a3pn;
            }
        }
    }
}

// ---------------------------------------------------------------------------
// Fallback: verified round-12 fused kernel (only if ws too small).
__global__ __launch_bounds__(256, 1) void ctc_scan_fb(
    const float* __restrict__ lp,
    const int*   __restrict__ targets,
    const int*   __restrict__ ilen,
    const int*   __restrict__ tlen,
    float*       __restrict__ v_out)
{
    const int n    = blockIdx.x;
    const int tid  = threadIdx.x;
    const int wv   = tid >> 6;
    const int lane = tid & 63;

    __shared__ float  s_rows[2][CH][CC];
    __shared__ float4 s_e[2][CH / 2][64];
    __shared__ float4 s_pb4[2][CH / 4];

    const int tgA = targets[n * SS + 2 * lane];
    const int tgB = targets[n * SS + 2 * lane + 1];
    const float* lpn = lp + (size_t)n * CC;
    const int w = wv - 1;

    auto issue_rows = [&](int c, int buf) {
#pragma unroll
        for (int i = 0; i < 6; ++i) {
            const int idx = 3 * i + w;
            if (idx < 16) {
                const int r = 2 * idx;
                int t = 1 + c * CH + r + (lane >> 5);
                if (t > TT - 1) t = TT - 1;
                const float* src = lpn + (size_t)t * NC + (lane & 31) * 4;
                __builtin_amdgcn_global_load_lds(
                    (const __attribute__((address_space(1))) void*)src,
                    (__attribute__((address_space(3))) void*)&s_rows[buf][r][0],
                    16, 0, 0);
            }
        }
    };
    auto gather = [&](int buf, int ebuf) {
#pragma unroll
        for (int i = 0; i < 6; ++i) {
            const int k = 3 * i + w;
            if (k < 16) {
                const int rA = 2 * k, rB = rA + 1;
                const float pa0 = s_rows[buf][rA][tgA], pc0 = s_rows[buf][rA][tgB];
                const float pa1 = s_rows[buf][rB][tgA], pc1 = s_rows[buf][rB][tgB];
                s_e[ebuf][k][lane] =
                    make_float4(__expf(pa0), __expf(pc0), __expf(pa1), __expf(pc1));
            }
        }
        if (w == 2 && lane < CH) {
            const float pbv = s_rows[buf][lane][0];
            ((float*)s_pb4[ebuf])[lane] = __expf(pbv);
        }
    };

    if (wv != 0) {
        issue_rows(0, 0);
        issue_rows(1, 1);
        if (w == 0) { VMC(6); } else { VMC(5); }
        gather(0, 0);
    }

    const int tgBm = (lane > 0) ? targets[n * SS + 2 * lane - 1] : -1;
    const float k1f = (lane > 0 && tgA != tgBm) ? 1.f : 0.f;
    const float k3f = (tgB != tgA) ? 1.f : 0.f;
    const int il    = ilen[n];
    const int vs    = 2 * tlen[n] - 1;
    const int vlane = vs >> 2;

    float a0 = 1.f, a1 = 1.f, a2 = 1.f, a3 = 1.f, ls = 0.f;
    if (wv == 0) {
        a0 = (lane == 0) ? __expf(lpn[0])   : 1.f;
        a1 = (lane == 0) ? __expf(lpn[tgA]) : 1.f;
    }
    float a3p = (lane == 0) ? 0.f : 1.f;
    float mr = 1.f, inv = 1.f;

    const unsigned base_e0  = (unsigned)(size_t)(void*)&s_e[0][0][lane];
    const unsigned base_pq0 = (unsigned)(size_t)(void*)&s_pb4[0][0];

    __syncthreads();
    if (wv == 0) __builtin_amdgcn_s_setprio(1);

    for (int cc = 0; cc < NCHUNK; ++cc) {
        const int b = cc & 1;
        if (wv == 0) {
            const int t0 = 1 + cc * CH;
            const bool cap = ((unsigned)(il - 1 - t0) < (unsigned)CH);
            const unsigned base_e  = base_e0  + (unsigned)(b << 14);
            const unsigned base_pq = base_pq0 + (unsigned)(b << 7);

            f4 gea[3], geb[3], gpq[3];
#define ISSUE(mi, oea, oeb, opq) do { \
    DSR(gea[mi], base_e, oea); DSR(geb[mi], base_e, oeb); \
    DSR(gpq[mi], base_pq, opq); } while (0)

            auto group4 = [&](const f4& ea, const f4& eb2, const f4& pq, int jbase) {
#pragma unroll
                for (int c = 0; c < 4; ++c) {
                    const int j = jbase + c;
                    const float cpa = (c==0)?ea[0]:(c==1)?ea[2]:(c==2)?eb2[0]:eb2[2];
                    const float cpc = (c==0)?ea[1]:(c==1)?ea[3]:(c==2)?eb2[1]:eb2[3];
                    const float cpb = pq[c];

                    float nb3 = fmaf(k3f, a1, a3 + a2) * cpc;
                    float a3pn = dpp_shr1(nb3);
                    float nb0 = (a0 + a3p) * cpb;
                    float nb1 = fmaf(k1f, a3p, a0 + a1) * cpa;
                    float nb2 = (a2 + a1) * cpb;

                    const int jj = j & 7;
                    if      (jj == 0) mr = fmaxf(fmaxf(nb0, nb1), fmaxf(nb2, nb3));
                    else if (jj == 1) mr = dpp_max_stage<DPP_QP_XOR1>(mr);
                    else if (jj == 2) mr = dpp_max_stage<DPP_QP_XOR2>(mr);
                    else if (jj == 3) mr = dpp_max_stage<DPP_HALF_MIRR>(mr);
                    else if (jj == 4) mr = dpp_max_stage<DPP_ROW_MIRR>(mr);
                    else if (jj == 5) mr = dpp_max_stage<DPP_BCAST15>(mr);
                    else if (jj == 6) mr = dpp_max_stage<DPP_BCAST31>(mr);
                    else {
                        const float mru = __int_as_float(
                            __builtin_amdgcn_readlane(__float_as_int(mr), 63));
                        inv = 1.0f / mru;
                        ls += __logf(mru);
                        nb0 *= inv; nb1 *= inv; nb2 *= inv; nb3 *= inv;
                    }

                    if (cap) {
                        const int t = t0 + j;
                        if (t == il - 1 && lane == vlane)
                            v_out[n] = __logf((vs & 2) ? nb3 : nb1) + ls;
                    }

                    a0 = nb0; a1 = nb1; a2 = nb2; a3 = nb3;
                    if (jj == 7) a3pn *= inv;
                    a3p = a3pn;
                }
            };

            ISSUE(0, 0,     1024,  0);
            ISSUE(1, 2048,  3072,  16);
            ISSUE(2, 4096,  5120,  32);  LGKM(6); group4(gea[0], geb[0], gpq[0], 0);
            ISSUE(0, 6144,  7168,  48);  LGKM(6); group4(gea[1], geb[1], gpq[1], 4);
            ISSUE(1, 8192,  9216,  64);  LGKM(6); group4(gea[2], geb[2], gpq[2], 8);
            ISSUE(2, 10240, 11264, 80);  LGKM(6); group4(gea[0], geb[0], gpq[0], 12);
            ISSUE(0, 12288, 13312, 96);  LGKM(6); group4(gea[1], geb[1], gpq[1], 16);
            ISSUE(1, 14336, 15360, 112); LGKM(6); group4(gea[2], geb[2], gpq[2], 20);
                                         LGKM(3); group4(gea[0], geb[0], gpq[0], 24);
                                         LGKM(0); group4(gea[1], geb[1], gpq[1], 28);
#undef ISSUE
        } else {
            issue_rows(cc + 2, cc & 1);
            if (w == 0) { VMC(6); } else { VMC(5); }
            if (cc + 1 < NCHUNK) gather((cc + 1) & 1, (cc + 1) & 1);
            asm volatile("s_waitcnt lgkmcnt(0)" ::: "memory");
        }
        BARRIER();
    }
}

// loss = -logsumexp(v) over the 64 batch elements; single wave
__global__ void ctc_reduce(const float* __restrict__ v, float* __restrict__ out)
{
    const int lane = threadIdx.x;
    float x = v[lane];
    float m = x;
#pragma unroll
    for (int off = 32; off > 0; off >>= 1) m = fmaxf(m, __shfl_xor(m, off));
    float e = __expf(x - m);
#pragma unroll
    for (int off = 32; off > 0; off >>= 1) e += __shfl_xor(e, off);
    if (lane == 0) out[0] = -(m + __logf(e));
}

extern "C" void kernel_launch(void* const* d_in, const int* in_sizes, int n_in,
                              void* d_out, int out_size, void* d_ws, size_t ws_size,
                              hipStream_t stream) {
    const float* lp      = (const float*)d_in[0];
    const int*   targets = (const int*)d_in[1];
    const int*   ilen    = (const int*)d_in[2];
    const int*   tlen    = (const int*)d_in[3];

    float* v   = (float*)d_ws;
    float* out = (float*)d_out;

    const size_t NEED = 256 + (size_t)TT * NN * 64 * sizeof(float4);  // 64 MiB + 256 B
    if (ws_size >= NEED) {
        float4* E = (float4*)((char*)d_ws + 256);
        ctc_emit<<<TT * NN / 4, 256, 0, stream>>>(lp, targets, E);
        ctc_scan_lone<<<NN, 64, 0, stream>>>(E, targets, ilen, tlen, v);
    } else {
        ctc_scan_fb<<<NN, 256, 0, stream>>>(lp, targets, ilen, tlen, v);
    }
    ctc_reduce<<<1, 64, 0, stream>>>(v, out);
}

// Round 18
// 71.704 us; speedup vs baseline: 1.4420x; 1.4420x over previous
//
#include <hip/hip_runtime.h>
#include <math.h>

#define TT 1024
#define NN 64
#define CC 128
#define SS 128
#define CH 32          // steps per chunk
#define NCHUNK 32      // chunks covering t = 1..1024
#define NC (NN * CC)   // floats between time rows

typedef float f4 __attribute__((ext_vector_type(4)));

// DPP controls (gfx9/CDNA encodings)
#define DPP_QP_XOR1   0xB1
#define DPP_QP_XOR2   0x4E
#define DPP_WAVE_SHR1 0x138
#define DPP_ROW_MIRR  0x140
#define DPP_HALF_MIRR 0x141
#define DPP_BCAST15   0x142
#define DPP_BCAST31   0x143

template <int CTRL>
__device__ __forceinline__ float dpp_max_stage(float v) {
    int p = __builtin_amdgcn_update_dpp(__float_as_int(v), __float_as_int(v),
                                        CTRL, 0xF, 0xF, false);
    return fmaxf(v, __int_as_float(p));
}
__device__ __forceinline__ float dpp_shr1(float v) {
    int p = __builtin_amdgcn_update_dpp(0, __float_as_int(v),
                                        DPP_WAVE_SHR1, 0xF, 0xF, true);
    return __int_as_float(p);
}

// inline-asm LDS read: cannot be rematerialized/sunk by the compiler
#define DSR(dst, addr, off) \
    asm volatile("ds_read_b128 %0, %1 offset:" #off : "=v"(dst) : "v"(addr))
#define LGKM(n) do { \
    asm volatile("s_waitcnt lgkmcnt(" #n ")" ::: "memory"); \
    __builtin_amdgcn_sched_barrier(0); } while (0)
#define VMC(n) do { \
    asm volatile("s_waitcnt vmcnt(" #n ")" ::: "memory"); \
    __builtin_amdgcn_sched_barrier(0); } while (0)
#define ISSUE(mi, oea, oeb, opq) do { \
    DSR(gea[mi], base_e, oea); DSR(geb[mi], base_e, oeb); \
    DSR(gpq[mi], base_pq, opq); } while (0)
#define BARRIER() asm volatile("s_barrier" ::: "memory")

// Fused producer/consumer CTC forward scan (round-9 verified, 71.5 us).
// One block per batch element n. 5 waves: wave 0 = consumer (serial
// recurrence in registers, asm ds_read pipeline with counted lgkmcnt),
// waves 1-4 = producers (coalesced global_load_lds row staging + LDS
// gather + exp + pack, counted vmcnt, raw s_barrier per chunk).
__global__ __launch_bounds__(320, 1) void ctc_scan(
    const float* __restrict__ lp,        // [T, N, C] fp32 log-softmax
    const int*   __restrict__ targets,   // [N, S]
    const int*   __restrict__ ilen,      // [N]
    const int*   __restrict__ tlen,      // [N]
    float*       __restrict__ v_out)     // [N] terminal log-alpha
{
    const int n    = blockIdx.x;
    const int tid  = threadIdx.x;
    const int wv   = tid >> 6;           // 0 = consumer, 1..4 = producers
    const int lane = tid & 63;

    __shared__ float  s_rows[2][CH][CC];    // 32 KiB: staged lp rows
    __shared__ float4 s_e[2][CH / 2][64];   // 32 KiB: packed emissions
    __shared__ float4 s_pb4[2][CH / 4];     // 256 B:  blank probs

    const int tgA = targets[n * SS + 2 * lane];
    const int tgB = targets[n * SS + 2 * lane + 1];
    const float* lpn = lp + (size_t)n * CC;

    const int w  = wv - 1;
    const int r0 = w * 8;

    auto issue_rows = [&](int c, int buf) {
#pragma unroll
        for (int i = 0; i < 4; ++i) {
            const int r = r0 + 2 * i;
            int t = 1 + c * CH + r + (lane >> 5);
            if (t > TT - 1) t = TT - 1;
            const float* src = lpn + (size_t)t * NC + (lane & 31) * 4;
            __builtin_amdgcn_global_load_lds(
                (const __attribute__((address_space(1))) void*)src,
                (__attribute__((address_space(3))) void*)&s_rows[buf][r][0],
                16, 0, 0);
        }
    };
    auto gather = [&](int buf, int ebuf) {
#pragma unroll
        for (int i = 0; i < 4; ++i) {
            const int rA = r0 + 2 * i, rB = rA + 1;
            const float pa0 = s_rows[buf][rA][tgA], pc0 = s_rows[buf][rA][tgB];
            const float pa1 = s_rows[buf][rB][tgA], pc1 = s_rows[buf][rB][tgB];
            s_e[ebuf][(r0 >> 1) + i][lane] =
                make_float4(__expf(pa0), __expf(pc0), __expf(pa1), __expf(pc1));
        }
        if (lane < 8) {
            const float pbv = s_rows[buf][r0 + lane][0];
            ((float*)s_pb4[ebuf])[r0 + lane] = __expf(pbv);
        }
    };

    if (wv != 0) {
        issue_rows(0, 0);
        issue_rows(1, 1);
        VMC(4);
        gather(0, 0);
    }

    const int tgBm = (lane > 0) ? targets[n * SS + 2 * lane - 1] : -1;
    const float k1f = (lane > 0 && tgA != tgBm) ? 1.f : 0.f;
    const float k3f = (tgB != tgA) ? 1.f : 0.f;
    const int il    = ilen[n];
    const int vs    = 2 * tlen[n] - 1;
    const int vlane = vs >> 2;

    float a0 = 1.f, a1 = 1.f, a2 = 1.f, a3 = 1.f, ls = 0.f;
    if (wv == 0) {
        a0 = (lane == 0) ? __expf(lpn[0])   : 1.f;
        a1 = (lane == 0) ? __expf(lpn[tgA]) : 1.f;
    }
    float a3p = (lane == 0) ? 0.f : 1.f;
    float mr = 1.f, inv = 1.f;

    const unsigned base_e0  = (unsigned)(size_t)(void*)&s_e[0][0][lane];
    const unsigned base_pq0 = (unsigned)(size_t)(void*)&s_pb4[0][0];

    __syncthreads();

    for (int cc = 0; cc < NCHUNK; ++cc) {
        const int b = cc & 1;
        if (wv == 0) {
            const int t0 = 1 + cc * CH;
            const bool cap = ((unsigned)(il - 1 - t0) < (unsigned)CH);
            const unsigned base_e  = base_e0  + (unsigned)(b << 14);
            const unsigned base_pq = base_pq0 + (unsigned)(b << 7);

            f4 gea[3], geb[3], gpq[3];

            auto group4 = [&](const f4& ea, const f4& eb, const f4& pq, int jbase) {
#pragma unroll
                for (int c = 0; c < 4; ++c) {
                    const int j = jbase + c;
                    const float cpa = (c==0)?ea[0]:(c==1)?ea[2]:(c==2)?eb[0]:eb[2];
                    const float cpc = (c==0)?ea[1]:(c==1)?ea[3]:(c==2)?eb[1]:eb[3];
                    const float cpb = pq[c];

                    float nb3 = fmaf(k3f, a1, a3 + a2) * cpc;
                    float a3pn = dpp_shr1(nb3);
                    float nb0 = (a0 + a3p) * cpb;
                    float nb1 = fmaf(k1f, a3p, a0 + a1) * cpa;
                    float nb2 = (a2 + a1) * cpb;

                    const int jj = j & 7;
                    if      (jj == 0) mr = fmaxf(fmaxf(nb0, nb1), fmaxf(nb2, nb3));
                    else if (jj == 1) mr = dpp_max_stage<DPP_QP_XOR1>(mr);
                    else if (jj == 2) mr = dpp_max_stage<DPP_QP_XOR2>(mr);
                    else if (jj == 3) mr = dpp_max_stage<DPP_HALF_MIRR>(mr);
                    else if (jj == 4) mr = dpp_max_stage<DPP_ROW_MIRR>(mr);
                    else if (jj == 5) mr = dpp_max_stage<DPP_BCAST15>(mr);
                    else if (jj == 6) mr = dpp_max_stage<DPP_BCAST31>(mr);
                    else {
                        const float mru = __int_as_float(
                            __builtin_amdgcn_readlane(__float_as_int(mr), 63));
                        inv = 1.0f / mru;
                        ls += __logf(mru);
                        nb0 *= inv; nb1 *= inv; nb2 *= inv; nb3 *= inv;
                    }

                    if (cap) {
                        const int t = t0 + j;
                        if (t == il - 1 && lane == vlane)
                            v_out[n] = __logf((vs & 2) ? nb3 : nb1) + ls;
                    }

                    a0 = nb0; a1 = nb1; a2 = nb2; a3 = nb3;
                    if (jj == 7) a3pn *= inv;
                    a3p = a3pn;
                }
            };

            ISSUE(0, 0,     1024,  0);
            ISSUE(1, 2048,  3072,  16);
            ISSUE(2, 4096,  5120,  32);  LGKM(6); group4(gea[0], geb[0], gpq[0], 0);
            ISSUE(0, 6144,  7168,  48);  LGKM(6); group4(gea[1], geb[1], gpq[1], 4);
            ISSUE(1, 8192,  9216,  64);  LGKM(6); group4(gea[2], geb[2], gpq[2], 8);
            ISSUE(2, 10240, 11264, 80);  LGKM(6); group4(gea[0], geb[0], gpq[0], 12);
            ISSUE(0, 12288, 13312, 96);  LGKM(6); group4(gea[1], geb[1], gpq[1], 16);
            ISSUE(1, 14336, 15360, 112); LGKM(6); group4(gea[2], geb[2], gpq[2], 20);
                                         LGKM(3); group4(gea[0], geb[0], gpq[0], 24);
                                         LGKM(0); group4(gea[1], geb[1], gpq[1], 28);
        } else {
            issue_rows(cc + 2, cc & 1);
            VMC(4);
            if (cc + 1 < NCHUNK) gather((cc + 1) & 1, (cc + 1) & 1);
            asm volatile("s_waitcnt lgkmcnt(0)" ::: "memory");
        }
        BARRIER();
    }
}

// loss = -logsumexp(v) over the 64 batch elements; single wave
__global__ void ctc_reduce(const float* __restrict__ v, float* __restrict__ out)
{
    const int lane = threadIdx.x;
    float x = v[lane];
    float m = x;
#pragma unroll
    for (int off = 32; off > 0; off >>= 1) m = fmaxf(m, __shfl_xor(m, off));
    float e = __expf(x - m);
#pragma unroll
    for (int off = 32; off > 0; off >>= 1) e += __shfl_xor(e, off);
    if (lane == 0) out[0] = -(m + __logf(e));
}

extern "C" void kernel_launch(void* const* d_in, const int* in_sizes, int n_in,
                              void* d_out, int out_size, void* d_ws, size_t ws_size,
                              hipStream_t stream) {
    const float* lp      = (const float*)d_in[0];
    const int*   targets = (const int*)d_in[1];
    const int*   ilen    = (const int*)d_in[2];
    const int*   tlen    = (const int*)d_in[3];

    float* v   = (float*)d_ws;    // 64 floats of scratch
    float* out = (float*)d_out;

    ctc_scan<<<NN, 320, 0, stream>>>(lp, targets, ilen, tlen, v);
    ctc_reduce<<<1, 64, 0, stream>>>(v, out);
}